// Round 4
// baseline (142.880 us; speedup 1.0000x reference)
//
#include <hip/hip_runtime.h>
#include <math.h>

#define N_DET 1344
#define NW 21        // max column words (N_DET/64)
#define MW_MAX 8     // Jacobi fast path supports M <= 512
#define T2S 9        // padded T2 row stride (u64) — breaks LDS bank conflicts
#define PAIR_CAP 40000

// ---------------- device helpers ----------------

__device__ __forceinline__ bool pt_in_quad4(const float* qx, const float* qy,
                                            float px, float py) {
    bool allp = true, alln = true;
#pragma unroll
    for (int k = 0; k < 4; k++) {
        int k1 = (k + 1) & 3;
        float ex = qx[k1] - qx[k], ey = qy[k1] - qy[k];
        float rx = px - qx[k],     ry = py - qy[k];
        float cr = ex * ry - ey * rx;
        allp = allp && (cr >= 0.f);
        alln = alln && (cr <= 0.f);
    }
    return allp || alln;
}

// Exact fp-order-matched intersection area (register-only bitonic sort).
__device__ float quad_inter_area(const float* Ax, const float* Ay,
                                 const float* Bx, const float* By) {
    float px[24], py[24];
    unsigned vmask = 0;
    int n = 0;
#pragma unroll
    for (int k = 0; k < 4; k++) {
        px[k] = Ax[k]; py[k] = Ay[k];
        if (pt_in_quad4(Bx, By, Ax[k], Ay[k])) { vmask |= 1u << k; n++; }
    }
#pragma unroll
    for (int k = 0; k < 4; k++) {
        px[4 + k] = Bx[k]; py[4 + k] = By[k];
        if (pt_in_quad4(Ax, Ay, Bx[k], By[k])) { vmask |= 1u << (4 + k); n++; }
    }
#pragma unroll
    for (int k = 0; k < 4; k++) {
        int k1 = (k + 1) & 3;
        float rax = Ax[k1] - Ax[k], ray = Ay[k1] - Ay[k];
#pragma unroll
        for (int l = 0; l < 4; l++) {
            int l1 = (l + 1) & 3;
            float rbx = Bx[l1] - Bx[l], rby = By[l1] - By[l];
            float qpx = Bx[l] - Ax[k],  qpy = By[l] - Ay[k];
            float den = rax * rby - ray * rbx;
            float ad  = fabsf(den);
            float dsafe = (ad < 1e-9f) ? 1e-9f : den;
            float t = (qpx * rby - qpy * rbx) / dsafe;
            float u = (qpx * ray - qpy * rax) / dsafe;
            bool ok = (ad > 1e-9f) && t >= 0.f && t <= 1.f && u >= 0.f && u <= 1.f;
            int id = 8 + k * 4 + l;
            px[id] = Ax[k] + t * rax;
            py[id] = Ay[k] + t * ray;
            if (ok) { vmask |= 1u << id; n++; }
        }
    }
    float cx = 0.f, cy = 0.f;
#pragma unroll
    for (int m = 0; m < 24; m++)
        if ((vmask >> m) & 1u) { cx += px[m]; cy += py[m]; }
    int mx = (n < 1) ? 1 : n;
    cx = cx / (float)mx;
    cy = cy / (float)mx;

    unsigned long long key[32];
    float sx[32], sy[32];
#pragma unroll
    for (int m = 0; m < 24; m++) {
        float rx = px[m] - cx, ry = py[m] - cy;
        float a = ((vmask >> m) & 1u) ? atan2f(ry, rx) : 1e9f;
        unsigned u = __float_as_uint(a);
        u = (u & 0x80000000u) ? ~u : (u | 0x80000000u);
        key[m] = (((unsigned long long)u) << 6) | (unsigned)m;
        sx[m] = rx; sy[m] = ry;
    }
#pragma unroll
    for (int m = 24; m < 32; m++) { key[m] = ~0ull; sx[m] = 0.f; sy[m] = 0.f; }

#pragma unroll
    for (int k = 2; k <= 32; k <<= 1) {
#pragma unroll
        for (int j = k >> 1; j > 0; j >>= 1) {
#pragma unroll
            for (int t = 0; t < 32; t++) {
                int l = t ^ j;
                if (l > t) {
                    bool up = ((t & k) == 0);
                    bool sw = up ? (key[t] > key[l]) : (key[t] < key[l]);
                    if (sw) {
                        unsigned long long tk = key[t]; key[t] = key[l]; key[l] = tk;
                        float tx = sx[t]; sx[t] = sx[l]; sx[l] = tx;
                        float ty = sy[t]; sy[t] = sy[l]; sy[l] = ty;
                    }
                }
            }
        }
    }

    unsigned ut = __float_as_uint(1e9f) | 0x80000000u;
    unsigned long long kt = ((unsigned long long)ut) << 6;
    float fx = sx[0], fy = sy[0];
    float qx2[24], qy2[24];
#pragma unroll
    for (int m = 0; m < 24; m++) {
        bool v = key[m] < kt;
        qx2[m] = v ? sx[m] : fx;
        qy2[m] = v ? sy[m] : fy;
    }
    float ssum = 0.f;
#pragma unroll
    for (int m = 0; m < 24; m++) {
        int m1 = (m + 1) % 24;
        ssum += qx2[m] * qy2[m1] - qy2[m] * qx2[m1];
    }
    float area = 0.5f * fabsf(ssum);
    return (n >= 3) ? area : 0.f;
}

__device__ bool iou_suppress(const float* __restrict__ cor, const float* __restrict__ a5,
                             int i, int j) {
    float Axr[4], Ayr[4], Bxr[4], Byr[4];
#pragma unroll
    for (int k = 0; k < 4; k++) {
        Axr[k] = cor[i * 8 + 2 * k]; Ayr[k] = cor[i * 8 + 2 * k + 1];
        Bxr[k] = cor[j * 8 + 2 * k]; Byr[k] = cor[j * 8 + 2 * k + 1];
    }
    float inter = quad_inter_area(Axr, Ayr, Bxr, Byr);
    float iou = inter / (a5[i] + a5[j] - inter + 1e-9f);
    return iou >= 0.2f;
}

// ---------------- K1: decode + min-area polygon + box/corners + circles ----------------
__global__ void k_decode(const float* __restrict__ out3, const float* __restrict__ out4,
                         const float* __restrict__ out5,
                         const float* __restrict__ o1l3, const float* __restrict__ o1l4,
                         const float* __restrict__ o1l5,
                         const float* __restrict__ ofl3, const float* __restrict__ ofl4,
                         const float* __restrict__ ofl5,
                         float* conf, float* cls0, float* cls1, float* xx, float* yy,
                         float* a5, float* ccx, float* ccy, float* rr,
                         float* rect, float* cor, int* mask, int* Mcnt, int* pairCnt) {
    int n = blockIdx.x * blockDim.x + threadIdx.x;
    if (n >= N_DET) return;
    if (n == 0) { *Mcnt = 0; *pairCnt = 0; }
    const float *out, *o1, *of;
    int w, idx; float stride;
    if (n < 1024)      { out = out3; o1 = o1l3; of = ofl3; w = 32; idx = n;        stride = 4.f; }
    else if (n < 1280) { out = out4; o1 = o1l4; of = ofl4; w = 16; idx = n - 1024; stride = 8.f; }
    else               { out = out5; o1 = o1l5; of = ofl5; w = 8;  idx = n - 1280; stride = 16.f; }
    int hw = w * w;
    int row = idx / w, col = idx % w;
    float cf = out[0 * hw + idx];
    float c0 = out[1 * hw + idx];
    float c1 = out[2 * hw + idx];
    float x  = out[3 * hw + idx] * stride + stride * (float)col;
    float y  = out[4 * hw + idx] * stride + stride * (float)row;

    float Pa[9], Pb[9];
    float minb = INFINITY, maxb = -INFINITY, mina = INFINITY, maxa = -INFINITY;
#pragma unroll
    for (int k = 0; k < 9; k++) {
        float a = of[(2 * k) * hw + idx]     + o1[(2 * k) * hw + idx]     + y;
        float b = of[(2 * k + 1) * hw + idx] + o1[(2 * k + 1) * hw + idx] + x;
        Pa[k] = a; Pb[k] = b;
        mina = fminf(mina, a); maxa = fmaxf(maxa, a);
        minb = fminf(minb, b); maxb = fmaxf(maxb, b);
    }
    float area = (maxb - minb) * (maxa - mina) / 40.0f;
    float sg = 1.0f / (1.0f + expf(-area));
    int m = (cf > 0.7f * sg) ? 1 : 0;

    float best = INFINITY, bc = 0.f, bs = 0.f;
    float bumin = 0.f, bumax = 0.f, bvmin = 0.f, bvmax = 0.f;
#pragma unroll
    for (int i = 0; i < 9; i++) {
#pragma unroll
        for (int j = i + 1; j < 9; j++) {
            float d0 = Pa[j] - Pa[i], d1 = Pb[j] - Pb[i];
            float nr = sqrtf(d0 * d0 + d1 * d1 + 1e-12f);
            float c = d0 / nr, s = d1 / nr;
            float umin = INFINITY, umax = -INFINITY, vmin = INFINITY, vmax = -INFINITY;
#pragma unroll
            for (int k = 0; k < 9; k++) {
                float u =  Pa[k] * c + Pb[k] * s;
                float v = -Pa[k] * s + Pb[k] * c;
                umin = fminf(umin, u); umax = fmaxf(umax, u);
                vmin = fminf(vmin, v); vmax = fmaxf(vmax, v);
            }
            float ar = (umax - umin) * (vmax - vmin);
            if (ar < best) { best = ar; bc = c; bs = s;
                             bumin = umin; bumax = umax; bvmin = vmin; bvmax = vmax; }
        }
    }
    float cu[4] = {bumin, bumax, bumax, bumin};
    float cv[4] = {bvmin, bvmin, bvmax, bvmax};
    float r8[8];
#pragma unroll
    for (int k = 0; k < 4; k++) {
        r8[2 * k]     = cu[k] * bc - cv[k] * bs;
        r8[2 * k + 1] = cu[k] * bs + cv[k] * bc;
    }
    float w5 = sqrtf((r8[0] - r8[2]) * (r8[0] - r8[2]) + (r8[1] - r8[3]) * (r8[1] - r8[3]));
    float h5 = sqrtf((r8[4] - r8[2]) * (r8[4] - r8[2]) + (r8[5] - r8[3]) * (r8[5] - r8[3]));
    float cx = (r8[1] + r8[3] + r8[5] + r8[7]) * 0.25f;
    float cy = (r8[0] + r8[2] + r8[4] + r8[6]) * 0.25f;
    float ang = atanf((r8[0] - r8[2]) / (r8[1] - r8[3]));
    float cs = cosf(ang), sn = sinf(ang);
    const float lxs[4] = {-0.5f, 0.5f, 0.5f, -0.5f};
    const float lys[4] = {-0.5f, -0.5f, 0.5f, 0.5f};
#pragma unroll
    for (int k = 0; k < 4; k++) {
        cor[n * 8 + 2 * k]     = cx + lxs[k] * w5 * cs - lys[k] * h5 * sn;
        cor[n * 8 + 2 * k + 1] = cy + lxs[k] * w5 * sn + lys[k] * h5 * cs;
    }
#pragma unroll
    for (int k = 0; k < 8; k++) rect[n * 8 + k] = r8[k];
    conf[n] = cf; cls0[n] = c0; cls1[n] = c1;
    xx[n] = x; yy[n] = y; a5[n] = w5 * h5; mask[n] = m;
    ccx[n] = cx; ccy[n] = cy;
    rr[n] = 0.5f * sqrtf(w5 * w5 + h5 * h5);   // circumradius (conservative-filter only)
}

// ---------------- K2: rank per candidate (one 64-lane block each) ----------------
__global__ __launch_bounds__(64) void k_order(const float* __restrict__ conf,
                                              const int* __restrict__ mask,
                                              int* order, int* Mcnt) {
    int b = blockIdx.x;
    int lane = threadIdx.x;
    int mb = mask[b];
    float ki = mb ? conf[b] : -INFINITY;
    int rank = 0;
    for (int j = lane; j < N_DET; j += 64) {
        float kj = mask[j] ? conf[j] : -INFINITY;
        rank += ((kj > ki) || (kj == ki && j > b)) ? 1 : 0;
    }
    for (int off = 32; off; off >>= 1) rank += __shfl_down(rank, off, 64);
    if (lane == 0) {
        order[rank] = b;
        if (mb) atomicAdd(Mcnt, 1);
    }
}

// ---------------- K3a: cheap tests + inside bits + wave-aggregated pair append ----------------
__global__ __launch_bounds__(256) void k_pairs_a(
        const float* __restrict__ rect, const float* __restrict__ cor,
        const float* __restrict__ a5,
        const float* __restrict__ xx, const float* __restrict__ yy,
        const float* __restrict__ ccx, const float* __restrict__ ccy,
        const float* __restrict__ rr,
        const int* __restrict__ order, const int* __restrict__ Mcnt,
        unsigned long long* __restrict__ S2, unsigned int* __restrict__ pairs,
        int* __restrict__ pairCnt) {
    int M = *Mcnt;
    if (M <= 0) return;
    int MW = (M + 63) >> 6;
    bool use_list = (MW <= MW_MAX);
    int lane  = threadIdx.x & 63;
    int gwave = (blockIdx.x * 256 + threadIdx.x) >> 6;
    int nwave = (gridDim.x * 256) >> 6;
    int total = M * MW;
    for (int t = gwave; t < total; t += nwave) {
        int p = t / MW;
        int w = t - p * MW;
        int i = order[p];
        int q = w * 64 + lane;
        bool valid = q < M;
        int j = valid ? order[q] : i;

        float cbi = ccx[i], cai = ccy[i], ri = rr[i];
        // inside prefilter: point (yy_j, xx_j) vs rect_i circumcircle
        float da = yy[j] - cai, db = xx[j] - cbi;
        float rin = ri + 0.1f;
        bool inside = false;
        if (da * da + db * db <= rin * rin) {
            float qxr[4], qyr[4];
#pragma unroll
            for (int k = 0; k < 4; k++) { qxr[k] = rect[i * 8 + 2 * k]; qyr[k] = rect[i * 8 + 2 * k + 1]; }
            inside = pt_in_quad4(qxr, qyr, yy[j], xx[j]);
        }
        bool bit = valid && inside;
        unsigned long long bb = __ballot(bit);
        if (lane == 0) S2[p * MW + w] = bb;

        // iou prefilter: circumcircles overlap?
        float ex = cbi - ccx[j], ey = cai - ccy[j];
        float rs = ri + rr[j] + 0.1f;
        bool iou_pos = valid && (q != p) && !bit && (ex * ex + ey * ey <= rs * rs);
        if (use_list) {
            unsigned long long pm = __ballot(iou_pos);
            if (pm) {
                int cw = __popcll(pm);
                int base = 0;
                if (lane == 0) base = atomicAdd(pairCnt, cw);
                base = __shfl(base, 0, 64);
                if (iou_pos) {
                    int pos = base + __popcll(pm & ((1ull << lane) - 1ull));
                    if (pos < PAIR_CAP) {
                        pairs[pos] = ((unsigned)p << 11) | (unsigned)q;
                    } else if (iou_suppress(cor, a5, i, j)) {  // overflow: exact inline (same word as our ballot store, same wave: ordered)
                        atomicOr(&S2[p * MW + w], 1ull << (q & 63));
                    }
                }
            }
        } else if (iou_pos) {
            if (iou_suppress(cor, a5, i, j))
                atomicOr(&S2[p * MW + w], 1ull << (q & 63));
        }
    }
}

// ---------------- K3b: exact intersection on compacted needy pairs ----------------
__global__ __launch_bounds__(256) void k_pairs_b(
        const float* __restrict__ cor, const float* __restrict__ a5,
        const int* __restrict__ order, const int* __restrict__ Mcnt,
        const int* __restrict__ pairCnt, const unsigned int* __restrict__ pairs,
        unsigned long long* __restrict__ S2) {
    int M = *Mcnt;
    int MW = (M + 63) >> 6;
    if (MW > MW_MAX) return;           // list unused in fallback mode
    int cnt = *pairCnt; if (cnt > PAIR_CAP) cnt = PAIR_CAP;
    int stride = gridDim.x * 256;
    for (int t = blockIdx.x * 256 + threadIdx.x; t < cnt; t += stride) {
        unsigned v = pairs[t];
        int p = (int)(v >> 11), q = (int)(v & 2047u);
        int i = order[p], j = order[q];
        if (iou_suppress(cor, a5, i, j))
            atomicOr(&S2[p * MW + (q >> 6)], 1ull << (q & 63));
    }
}

// ---------------- K4: transpose + single-wave Gauss-Seidel NMS + outputs ----------------
__global__ __launch_bounds__(512) void k_scan_out(
    const float* __restrict__ cls0, const float* __restrict__ cls1,
    const float* __restrict__ xx, const float* __restrict__ yy,
    const float* __restrict__ rect,
    const int* __restrict__ order, const int* __restrict__ Mcnt,
    const unsigned long long* __restrict__ S2, float* __restrict__ out) {
    __shared__ int order_s[N_DET];
    __shared__ unsigned long long T2[512 * T2S];
    __shared__ unsigned long long Kfin[MW_MAX];
    __shared__ unsigned int keep32[(N_DET + 31) / 32];
    __shared__ int cnt_s[2];
    int tid = threadIdx.x;
    int lane = tid & 63, wid = tid >> 6;   // 8 waves
    int M = *Mcnt;
    int MW = (M + 63) >> 6;
    for (int t = tid; t < N_DET; t += 512) order_s[t] = order[t];
    for (int t = tid; t < (N_DET + 31) / 32; t += 512) keep32[t] = 0u;
    if (tid < 2) cnt_s[tid] = 0;
    if (tid < MW_MAX) Kfin[tid] = 0ull;
    __syncthreads();

    if (M > 0 && MW <= MW_MAX) {
        // --- bit-transpose S2 -> T2 (64x64 blocks via ballots), 8 waves ---
        for (int blk = wid; blk < MW * MW; blk += 8) {
            int wp = blk / MW, wq = blk - wp * MW;
            int pp = wp * 64 + lane;
            unsigned long long x = (pp < M) ? S2[pp * MW + wq] : 0ull;
#pragma unroll
            for (int b = 0; b < 64; b++) {
                unsigned long long bb = __ballot((x >> b) & 1ull);
                if (lane == b) T2[(wq * 64 + b) * T2S + wp] = bb;
            }
        }
        __syncthreads();

        // --- single-wave Gauss-Seidel fixed point: keep[q] = !any(p<q, keep[p] & S[p][q]) ---
        // ballot broadcasts each updated word to all lanes -> zero barriers.
        if (wid == 0) {
            unsigned long long kw[MW_MAX];
#pragma unroll
            for (int w = 0; w < MW_MAX; w++) {
                int lo = w * 64;
                kw[w] = (M > lo) ? ((M - lo >= 64) ? ~0ull : ((1ull << (M - lo)) - 1ull)) : 0ull;
            }
            unsigned long long pmask = lane ? ((1ull << lane) - 1ull) : 0ull;
            for (int it = 0; it <= M; ++it) {
                bool changed = false;
#pragma unroll
                for (int k = 0; k < MW_MAX; k++) {
                    if (k < MW) {
                        int q = k * 64 + lane;
                        const unsigned long long* row = &T2[q * T2S];
                        unsigned long long sup = 0ull;
#pragma unroll
                        for (int w = 0; w < MW_MAX; w++) {
                            if (w < k)       sup |= row[w] & kw[w];
                            else if (w == k) sup |= row[w] & kw[w] & pmask;
                        }
                        bool nb = (q < M) && (sup == 0ull);
                        unsigned long long nw = __ballot(nb);
                        changed |= (nw != kw[k]);
                        kw[k] = nw;
                    }
                }
                if (!changed) break;
            }
            if (lane == 0) {
#pragma unroll
                for (int w = 0; w < MW_MAX; w++) Kfin[w] = kw[w];
            }
        }
        __syncthreads();
        for (int t = tid; t < M; t += 512) {
            if ((Kfin[t >> 6] >> (t & 63)) & 1ull) {
                int i = order_s[t];
                atomicOr(&keep32[i >> 5], 1u << (i & 31));
            }
        }
    } else if (M > 0) {
        // --- generic sequential fallback (M > 512) ---
        if (wid == 0) {
            unsigned long long rem = 0ull;
            int lo = lane * 64;
            if (M > lo) rem = (M - lo >= 64) ? ~0ull : ((1ull << (M - lo)) - 1ull);
            for (int guard = 0; guard < N_DET; guard++) {
                unsigned long long vote = __ballot(rem != 0ull);
                if (!vote) break;
                int w = __builtin_ctzll(vote);
                unsigned long long wd = __shfl(rem, w, 64);
                int b = __builtin_ctzll(wd);
                int p = w * 64 + b;
                int i = order_s[p];
                if (lane == 0) atomicOr(&keep32[i >> 5], 1u << (i & 31));
                unsigned long long rowv = (lane < MW) ? S2[p * MW + lane] : 0ull;
                rem &= ~rowv;
                if (lane == w) rem &= ~(1ull << b);
            }
        }
    }
    __syncthreads();

    int c0 = 0, c1 = 0;
    for (int n = tid; n < N_DET; n += 512) {
        bool kp = (keep32[n >> 5] >> (n & 31)) & 1u;
        float a = cls0[n], b = cls1[n];
        float mxc = fmaxf(a, b);
        bool m0 = kp && (a == mxc);
        bool m1 = kp && (b == mxc);
        float x = xx[n], y = yy[n];
        out[2 + 0 * N_DET * 2 + n * 2 + 0] = m0 ? x : 0.f;
        out[2 + 0 * N_DET * 2 + n * 2 + 1] = m0 ? y : 0.f;
        out[2 + 1 * N_DET * 2 + n * 2 + 0] = m1 ? x : 0.f;
        out[2 + 1 * N_DET * 2 + n * 2 + 1] = m1 ? y : 0.f;
        float kf = kp ? 1.f : 0.f;
#pragma unroll
        for (int k = 0; k < 8; k++)
            out[2 + 2 * N_DET * 2 + n * 8 + k] = rect[n * 8 + k] * kf;
        c0 += m0 ? 1 : 0;
        c1 += m1 ? 1 : 0;
    }
    if (c0) atomicAdd(&cnt_s[0], c0);
    if (c1) atomicAdd(&cnt_s[1], c1);
    __syncthreads();
    if (tid == 0) { out[0] = (float)cnt_s[0]; out[1] = (float)cnt_s[1]; }
}

// ---------------- launch ----------------
extern "C" void kernel_launch(void* const* d_in, const int* in_sizes, int n_in,
                              void* d_out, int out_size, void* d_ws, size_t ws_size,
                              hipStream_t stream) {
    const float* out3 = (const float*)d_in[0];
    const float* out4 = (const float*)d_in[1];
    const float* out5 = (const float*)d_in[2];
    const float* o1l3 = (const float*)d_in[3];
    const float* o1l4 = (const float*)d_in[4];
    const float* o1l5 = (const float*)d_in[5];
    const float* ofl3 = (const float*)d_in[6];
    const float* ofl4 = (const float*)d_in[7];
    const float* ofl5 = (const float*)d_in[8];
    float* out = (float*)d_out;

    const int N = N_DET;
    float* wsf  = (float*)d_ws;
    float* conf = wsf + 0 * N;
    float* cls0 = wsf + 1 * N;
    float* cls1 = wsf + 2 * N;
    float* xx   = wsf + 3 * N;
    float* yy   = wsf + 4 * N;
    float* a5   = wsf + 5 * N;
    float* ccx  = wsf + 6 * N;
    float* ccy  = wsf + 7 * N;
    float* rr   = wsf + 8 * N;
    float* rect = wsf + 9 * N;       // 8N
    float* cor  = wsf + 17 * N;      // 8N
    int* mask   = (int*)(wsf + 25 * N);  // N
    int* order  = mask + N;              // N
    int* Mcnt   = order + N;
    int* pairCnt = Mcnt + 1;
    unsigned long long* S2 = (unsigned long long*)(wsf + 27 * N + 4);   // N*NW u64 max
    unsigned int* pairs = (unsigned int*)((char*)S2 + 32768);           // past fast-path S2 extent

    k_decode<<<(N + 255) / 256, 256, 0, stream>>>(out3, out4, out5, o1l3, o1l4, o1l5,
                                                  ofl3, ofl4, ofl5,
                                                  conf, cls0, cls1, xx, yy, a5,
                                                  ccx, ccy, rr, rect, cor, mask, Mcnt, pairCnt);
    k_order<<<N, 64, 0, stream>>>(conf, mask, order, Mcnt);
    k_pairs_a<<<1024, 256, 0, stream>>>(rect, cor, a5, xx, yy, ccx, ccy, rr,
                                        order, Mcnt, S2, pairs, pairCnt);
    k_pairs_b<<<64, 256, 0, stream>>>(cor, a5, order, Mcnt, pairCnt, pairs, S2);
    k_scan_out<<<1, 512, 0, stream>>>(cls0, cls1, xx, yy, rect, order, Mcnt, S2, out);
}